// Round 11
// baseline (81.028 us; speedup 1.0000x reference)
//
#include <hip/hip_runtime.h>
#include <math.h>

#define NUM_EMB 512
#define DIMV 65          // 65
#define DD   64          // DIM-1
#define BB   2048
#define NN   256
#define TPB  8           // 64-row tiles per block
#define GRID_APPLY ((BB * NN) / (64 * TPB))   // 1024 blocks
#define TFLOATS (64 * DIMV)                   // 4160 floats per tile
#define TVEC4   (TFLOATS / 4)                 // 1040 = 4*256 + 16

typedef short short8 __attribute__((ext_vector_type(8)));   // 8 bf16 (4 VGPR)
typedef float f32x4  __attribute__((ext_vector_type(4)));   // MFMA acc

__device__ __forceinline__ float gelu_exact(float x) {
    return 0.5f * x * (1.0f + erff(x * 0.7071067811865475f));
}

// fp32 -> bf16, round-to-nearest-even, deterministic
__device__ __forceinline__ unsigned f2bf_u(float f) {
    unsigned u = __builtin_bit_cast(unsigned, f);
    u += 0x7FFFu + ((u >> 16) & 1u);
    return u >> 16;
}
__device__ __forceinline__ unsigned short f2bf(float f) {
    return (unsigned short)f2bf_u(f);
}

// ---------------------------------------------------------------------------
// Kernel 1: build W[e] = H0 @ ... @ H63 (Householder matvec + rank-1 update),
// scale last column, store TRANSPOSED bf16: WgT[e][c][d] = bf16(W[e][d][c]).
// Rows of WgT are 128 B -> 16B-aligned short8 fragment loads in apply_W.
// Echoes r_idx into the out tail.
// ---------------------------------------------------------------------------
__global__ __launch_bounds__(256) void build_W(const float* __restrict__ emb,
                                               const float* __restrict__ flip_sign,
                                               const int*   __restrict__ r_idx,
                                               unsigned short* __restrict__ WgT,
                                               float* __restrict__ out) {
    __shared__ float v_lds[DD * DD];
    __shared__ float s_lds[DD];
    const int e = blockIdx.x;
    const int t = threadIdx.x;
    const int r = t >> 2;
    const int q = t & 3;

    const float* erow = emb + (size_t)e * (DD * DD);
    #pragma unroll
    for (int p = 0; p < 16; ++p) {
        int idx = p * 256 + t;
        v_lds[idx] = gelu_exact(erow[idx]);
    }

    // r_idx passthrough: output 1 lives at out[BB*NN*DIMV + b]
    if (t < 4) {
        int bi = e * 4 + t;
        out[(size_t)BB * NN * DIMV + bi] = (float)r_idx[bi];
    }
    __syncthreads();

    {
        const float* vr = &v_lds[r * DD + q * 16];
        float ss = 0.f;
        #pragma unroll
        for (int k = 0; k < 16; ++k) ss += vr[k] * vr[k];
        ss += __shfl_xor(ss, 1);
        ss += __shfl_xor(ss, 2);
        if (q == 0) s_lds[r] = 2.0f / ss;
    }
    __syncthreads();

    float Wq[16];
    #pragma unroll
    for (int k = 0; k < 16; ++k) Wq[k] = ((q * 16 + k) == r) ? 1.0f : 0.0f;

    float vv[16], nv[16];
    {
        const float* vr = &v_lds[q * 16];
        *(float4*)&nv[0]  = *(const float4*)&vr[0];
        *(float4*)&nv[4]  = *(const float4*)&vr[4];
        *(float4*)&nv[8]  = *(const float4*)&vr[8];
        *(float4*)&nv[12] = *(const float4*)&vr[12];
    }

    for (int w = 0; w < DD; ++w) {
        #pragma unroll
        for (int k = 0; k < 16; ++k) vv[k] = nv[k];
        if (w < DD - 1) {
            const float* vr = &v_lds[(w + 1) * DD + q * 16];
            *(float4*)&nv[0]  = *(const float4*)&vr[0];
            *(float4*)&nv[4]  = *(const float4*)&vr[4];
            *(float4*)&nv[8]  = *(const float4*)&vr[8];
            *(float4*)&nv[12] = *(const float4*)&vr[12];
        }
        float p0 = Wq[0] * vv[0],  p1 = Wq[1] * vv[1];
        float p2 = Wq[2] * vv[2],  p3 = Wq[3] * vv[3];
        #pragma unroll
        for (int k = 4; k < 16; k += 4) {
            p0 += Wq[k]     * vv[k];
            p1 += Wq[k + 1] * vv[k + 1];
            p2 += Wq[k + 2] * vv[k + 2];
            p3 += Wq[k + 3] * vv[k + 3];
        }
        float p = (p0 + p1) + (p2 + p3);
        p += __shfl_xor(p, 1);
        p += __shfl_xor(p, 2);
        const float sc = s_lds[w] * p;
        #pragma unroll
        for (int k = 0; k < 16; ++k) Wq[k] -= sc * vv[k];
    }

    if (q == 3) Wq[15] *= flip_sign[0];

    // store transposed bf16: WgT[e][c][d] with c = 16q+k, d = r
    unsigned short* wd = WgT + (size_t)e * (DD * DD) + r;
    #pragma unroll
    for (int k = 0; k < 16; ++k)
        wd[(16 * q + k) * DD] = f2bf(Wq[k]);
}

// ---------------------------------------------------------------------------
// Kernel 2 (MFMA, persistent double-buffered pipeline, counted vmcnt):
//   out[.,0]=x[.,0]; out[.,1+c]=sum_d x[.,1+d]*W[d][c]
// Grid 1024 x 256thr; block owns 8 consecutive 64-row tiles (2 b's).
// Per iteration i (fully unrolled, all indices static):
//   1. issue float4 loads of tile i+1 -> regs v[J^1]  (stay in flight)
//   2. ds_write_b128 tile i image from v[J]  (compiler emits COUNTED
//      vmcnt wait for v[J] only -- tile i+1 loads remain outstanding)
//   3. asm lgkmcnt(0); RAW s_barrier (no vmcnt drain, unlike __syncthreads)
//   4. wave w computes rows [16w,16w+16): f2bf-pack A-frags from image,
//      8x mfma_f32_16x16x32_bf16 vs global-loaded B-frags (L2/L3-hot),
//      epilogue acc -> image cols 1..64 (col-0 survives from load)
//   5. asm lgkmcnt(0); raw barrier; float4 store of the image
// Loads for tile i+1 overlap phases 2-5 of tile i => continuous streams.
// Buffer reuse distance = 2 barriers => race-free (per-wave rows in phase 4).
// LDS 33280 B -> 4 blocks/CU (16 waves).
// ---------------------------------------------------------------------------
__global__ __launch_bounds__(256) void apply_W(const float* __restrict__ x,
                                               const int*   __restrict__ r_idx,
                                               const unsigned short* __restrict__ WgT,
                                               float* __restrict__ out) {
    __shared__ alignas(16) float X[2][TFLOATS];   // 2 x 16640 B
    const int t = threadIdx.x;
    const int w = t >> 6;
    const int l = t & 63;
    const int lrow  = l & 15;
    const int kslot = l >> 4;
    const int r0    = w * 16;          // wave's rows within the 64-row tile

    const int tile0 = blockIdx.x * TPB;
    const int b0    = tile0 >> 2;      // 4 tiles per b; block spans 2 b's

    int e0 = r_idx[b0];
    int e1 = r_idx[b0 + 1];

    float4 v[2][4];
    float4 vt[2];
    short8 bfrg[4][2];

    // ---- prologue: tile-0 loads + B frags for b0 ----
    {
        const float4* xs = (const float4*)(x + (size_t)tile0 * TFLOATS);
        #pragma unroll
        for (int p = 0; p < 4; ++p) v[0][p] = xs[p * 256 + t];
        if (t < 16) vt[0] = xs[1024 + t];
    }
    {
        const unsigned short* wb = WgT + (size_t)e0 * (DD * DD);
        #pragma unroll
        for (int ct = 0; ct < 4; ++ct)
            #pragma unroll
            for (int kb = 0; kb < 2; ++kb)
                bfrg[ct][kb] = *(const short8*)(wb + (ct * 16 + lrow) * DD + kb * 32 + kslot * 8);
    }

    #pragma unroll
    for (int i = 0; i < TPB; ++i) {
        const int J = i & 1;

        // ---- 1. issue next-tile loads (deep, stay in flight) ----
        if (i + 1 < TPB) {
            const float4* xs = (const float4*)(x + (size_t)(tile0 + i + 1) * TFLOATS);
            #pragma unroll
            for (int p = 0; p < 4; ++p) v[J ^ 1][p] = xs[p * 256 + t];
            if (t < 16) vt[J ^ 1] = xs[1024 + t];
        }
        // B frags for second b (static at i==4 after unroll)
        if (i == 4) {
            const unsigned short* wb = WgT + (size_t)e1 * (DD * DD);
            #pragma unroll
            for (int ct = 0; ct < 4; ++ct)
                #pragma unroll
                for (int kb = 0; kb < 2; ++kb)
                    bfrg[ct][kb] = *(const short8*)(wb + (ct * 16 + lrow) * DD + kb * 32 + kslot * 8);
        }

        // ---- 2. image write (counted vmcnt wait on v[J] only) ----
        {
            float4* Xv = (float4*)X[J];
            #pragma unroll
            for (int p = 0; p < 4; ++p) Xv[p * 256 + t] = v[J][p];
            if (t < 16) Xv[1024 + t] = vt[J];
        }

        // ---- 3. writer-side LDS drain + raw barrier (no vmcnt drain) ----
        asm volatile("s_waitcnt lgkmcnt(0)" ::: "memory");
        __builtin_amdgcn_s_barrier();
        __builtin_amdgcn_sched_barrier(0);

        // ---- 4. compute: A-frags, MFMA, epilogue into image ----
        short8 afrg[2];
        #pragma unroll
        for (int kb = 0; kb < 2; ++kb) {
            const float* xp = &X[J][(r0 + lrow) * DIMV + 1 + kb * 32 + kslot * 8];
            union { short8 s; unsigned u[4]; } af;
            #pragma unroll
            for (int jj = 0; jj < 4; ++jj)
                af.u[jj] = f2bf_u(xp[2 * jj]) | (f2bf_u(xp[2 * jj + 1]) << 16);
            afrg[kb] = af.s;
        }

        f32x4 acc[4];
        #pragma unroll
        for (int ct = 0; ct < 4; ++ct) {
            f32x4 c0 = {0.f, 0.f, 0.f, 0.f};
            c0 = __builtin_amdgcn_mfma_f32_16x16x32_bf16(afrg[0], bfrg[ct][0], c0, 0, 0, 0);
            c0 = __builtin_amdgcn_mfma_f32_16x16x32_bf16(afrg[1], bfrg[ct][1], c0, 0, 0, 0);
            acc[ct] = c0;
        }

        // C/D layout: col = lane&15, row = (lane>>4)*4 + reg (HW-verified)
        #pragma unroll
        for (int ct = 0; ct < 4; ++ct)
            #pragma unroll
            for (int rg = 0; rg < 4; ++rg)
                X[J][(r0 + kslot * 4 + rg) * DIMV + 1 + ct * 16 + lrow] = acc[ct][rg];

        // ---- 5. epilogue drain + raw barrier, then float4 store ----
        asm volatile("s_waitcnt lgkmcnt(0)" ::: "memory");
        __builtin_amdgcn_s_barrier();
        __builtin_amdgcn_sched_barrier(0);

        {
            float4* og = (float4*)(out + (size_t)(tile0 + i) * TFLOATS);
            const float4* Xv = (const float4*)X[J];
            #pragma unroll
            for (int p = 0; p < 4; ++p) og[p * 256 + t] = Xv[p * 256 + t];
            if (t < 16) og[1024 + t] = Xv[1024 + t];
        }
    }
}

extern "C" void kernel_launch(void* const* d_in, const int* in_sizes, int n_in,
                              void* d_out, int out_size, void* d_ws, size_t ws_size,
                              hipStream_t stream) {
    const float* x         = (const float*)d_in[0];
    const int*   r_idx     = (const int*)d_in[1];
    const float* emb       = (const float*)d_in[2];
    const float* flip_sign = (const float*)d_in[3];
    float* out = (float*)d_out;
    unsigned short* WgT = (unsigned short*)d_ws;   // 512*64*64*2 = 4 MB bf16 W^T

    build_W<<<NUM_EMB, 256, 0, stream>>>(emb, flip_sign, r_idx, WgT, out);
    apply_W<<<GRID_APPLY, 256, 0, stream>>>(x, r_idx, WgT, out);
}

// Round 13
// 79.541 us; speedup vs baseline: 1.0187x; 1.0187x over previous
//
#include <hip/hip_runtime.h>
#include <math.h>

#define NUM_EMB 512
#define DIMV 65          // 65
#define DD   64          // DIM-1
#define BB   2048
#define NN   256
#define IMGF (16 * DIMV)                 // 1040 floats per 16-row wave image

typedef short short8 __attribute__((ext_vector_type(8)));   // 8 bf16 (4 VGPR)
typedef float f32x4  __attribute__((ext_vector_type(4)));   // MFMA acc
typedef float f4u    __attribute__((ext_vector_type(4), aligned(4)));  // 4B-aligned float4

__device__ __forceinline__ float gelu_exact(float x) {
    return 0.5f * x * (1.0f + erff(x * 0.7071067811865475f));
}

// fp32 -> bf16, round-to-nearest-even, deterministic
__device__ __forceinline__ unsigned f2bf_u(float f) {
    unsigned u = __builtin_bit_cast(unsigned, f);
    u += 0x7FFFu + ((u >> 16) & 1u);
    return u >> 16;
}
__device__ __forceinline__ unsigned short f2bf(float f) {
    return (unsigned short)f2bf_u(f);
}

// ---------------------------------------------------------------------------
// Kernel 1: build W[e] = H0 @ ... @ H63 (Householder matvec + rank-1 update),
// scale last column, store TRANSPOSED bf16: WgT[e][c][d] = bf16(W[e][d][c]).
// Echoes r_idx into the out tail.
// ---------------------------------------------------------------------------
__global__ __launch_bounds__(256) void build_W(const float* __restrict__ emb,
                                               const float* __restrict__ flip_sign,
                                               const int*   __restrict__ r_idx,
                                               unsigned short* __restrict__ WgT,
                                               float* __restrict__ out) {
    __shared__ float v_lds[DD * DD];
    __shared__ float s_lds[DD];
    const int e = blockIdx.x;
    const int t = threadIdx.x;
    const int r = t >> 2;
    const int q = t & 3;

    const float* erow = emb + (size_t)e * (DD * DD);
    #pragma unroll
    for (int p = 0; p < 16; ++p) {
        int idx = p * 256 + t;
        v_lds[idx] = gelu_exact(erow[idx]);
    }

    // r_idx passthrough: output 1 lives at out[BB*NN*DIMV + b]
    if (t < 4) {
        int bi = e * 4 + t;
        out[(size_t)BB * NN * DIMV + bi] = (float)r_idx[bi];
    }
    __syncthreads();

    {
        const float* vr = &v_lds[r * DD + q * 16];
        float ss = 0.f;
        #pragma unroll
        for (int k = 0; k < 16; ++k) ss += vr[k] * vr[k];
        ss += __shfl_xor(ss, 1);
        ss += __shfl_xor(ss, 2);
        if (q == 0) s_lds[r] = 2.0f / ss;
    }
    __syncthreads();

    float Wq[16];
    #pragma unroll
    for (int k = 0; k < 16; ++k) Wq[k] = ((q * 16 + k) == r) ? 1.0f : 0.0f;

    float vv[16], nv[16];
    {
        const float* vr = &v_lds[q * 16];
        *(float4*)&nv[0]  = *(const float4*)&vr[0];
        *(float4*)&nv[4]  = *(const float4*)&vr[4];
        *(float4*)&nv[8]  = *(const float4*)&vr[8];
        *(float4*)&nv[12] = *(const float4*)&vr[12];
    }

    for (int w = 0; w < DD; ++w) {
        #pragma unroll
        for (int k = 0; k < 16; ++k) vv[k] = nv[k];
        if (w < DD - 1) {
            const float* vr = &v_lds[(w + 1) * DD + q * 16];
            *(float4*)&nv[0]  = *(const float4*)&vr[0];
            *(float4*)&nv[4]  = *(const float4*)&vr[4];
            *(float4*)&nv[8]  = *(const float4*)&vr[8];
            *(float4*)&nv[12] = *(const float4*)&vr[12];
        }
        float p0 = Wq[0] * vv[0],  p1 = Wq[1] * vv[1];
        float p2 = Wq[2] * vv[2],  p3 = Wq[3] * vv[3];
        #pragma unroll
        for (int k = 4; k < 16; k += 4) {
            p0 += Wq[k]     * vv[k];
            p1 += Wq[k + 1] * vv[k + 1];
            p2 += Wq[k + 2] * vv[k + 2];
            p3 += Wq[k + 3] * vv[k + 3];
        }
        float p = (p0 + p1) + (p2 + p3);
        p += __shfl_xor(p, 1);
        p += __shfl_xor(p, 2);
        const float sc = s_lds[w] * p;
        #pragma unroll
        for (int k = 0; k < 16; ++k) Wq[k] -= sc * vv[k];
    }

    if (q == 3) Wq[15] *= flip_sign[0];

    // store transposed bf16: WgT[e][c][d] with c = 16q+k, d = r
    unsigned short* wd = WgT + (size_t)e * (DD * DD) + r;
    #pragma unroll
    for (int k = 0; k < 16; ++k)
        wd[(16 * q + k) * DD] = f2bf(Wq[k]);
}

// ---------------------------------------------------------------------------
// Kernel 2 (MFMA, wave-autonomous, ZERO barriers, all loads pre-issued):
//   out[.,0]=x[.,0]; out[.,1+c]=sum_d x[.,1+d]*W[d][c]
// Grid 2048 x 256thr = 8192 waves; wave gw owns 64 consecutive rows
// (= quarter of b = gw>>2, so ONE B-matrix per wave), as 4 x 16-row tiles.
// Each wave has a PRIVATE 1040-float LDS image -> no __syncthreads at all;
// only wave-local lgkmcnt ordering.
// Structure (fully unrolled, static indices):
//   0. issue B-frags (8x16B, L2-hot) + ALL 4 tiles' A-loads (4x dwordx4
//      per tile per lane, 4B-aligned 16B/lane -> 1KB/wave-instr) + 4 x0
//      dwords; sched_barrier(0) so nothing sinks. ~20 loads in flight/wave.
//   1. per tile: counted vmcnt wait (compiler) -> f2bf pack -> 8 MFMA ->
//      epilogue into image (<=4-way bank, m136: 1.58x ok) -> wave-local
//      lgkmcnt(0) -> 4.06 float4 stores (contiguous).
// Tiles 1-3's loads stay in flight under tiles 0-2 compute+stores:
// ~12 waves/CU x 5KB = 60KB outstanding per CU, continuous streams.
// (R12 bug was ONLY the launch: grid BB*8 instead of BB -> 8x OOB. Grid
//  must be BB = (BB*NN)/(4 waves * 64 rows) = 2048.)
// ---------------------------------------------------------------------------
__global__ __launch_bounds__(256) void apply_W(const float* __restrict__ x,
                                               const int*   __restrict__ r_idx,
                                               const unsigned short* __restrict__ WgT,
                                               float* __restrict__ out) {
    __shared__ alignas(16) float IMG[4][IMGF];   // 4 waves x 4160 B = 16640 B
    const int t = threadIdx.x;
    const int w = t >> 6;
    const int l = t & 63;
    const int lrow  = l & 15;
    const int kslot = l >> 4;

    const int gw = blockIdx.x * 4 + w;           // global wave id (< 8192)
    const size_t row0 = (size_t)gw * 64;         // wave's 64 rows
    const int b = gw >> 2;                       // one b per wave

    const int e = r_idx[b];                      // uniform scalar
    float* img = IMG[w];

    // ---- 0a. B fragments (once per wave; L2/L3-hot 8KB table) ----
    const unsigned short* wb = WgT + (size_t)e * (DD * DD);
    short8 bfrg[4][2];
    #pragma unroll
    for (int ct = 0; ct < 4; ++ct)
        #pragma unroll
        for (int kb = 0; kb < 2; ++kb)
            bfrg[ct][kb] = *(const short8*)(wb + (ct * 16 + lrow) * DD + kb * 32 + kslot * 8);

    // ---- 0b. issue ALL A-loads + x0 loads for the 4 tiles ----
    f4u   av[4][4];      // [tile][kb*2+seg] : 16 floats of A row-slice
    float x0v[4];
    #pragma unroll
    for (int i = 0; i < 4; ++i) {
        const float* xr = x + (row0 + i * 16 + lrow) * DIMV + 1 + kslot * 8;
        av[i][0] = *(const f4u*)(xr);            // kb=0, floats 0..3
        av[i][1] = *(const f4u*)(xr + 4);        // kb=0, floats 4..7
        av[i][2] = *(const f4u*)(xr + 32);       // kb=1, floats 0..3
        av[i][3] = *(const f4u*)(xr + 36);       // kb=1, floats 4..7
        x0v[i] = (l < 16) ? x[(row0 + i * 16 + l) * DIMV] : 0.f;
    }
    __builtin_amdgcn_sched_barrier(0);

    // ---- per-tile compute + store (no barriers; counted vmcnt per tile) ----
    #pragma unroll
    for (int i = 0; i < 4; ++i) {
        // f2bf pack A fragments (waits only on tile i's loads)
        short8 afrg[2];
        #pragma unroll
        for (int kb = 0; kb < 2; ++kb) {
            union { short8 s; unsigned u[4]; } af;
            const f4u a0 = av[i][kb * 2 + 0];
            const f4u a1 = av[i][kb * 2 + 1];
            af.u[0] = f2bf_u(a0.x) | (f2bf_u(a0.y) << 16);
            af.u[1] = f2bf_u(a0.z) | (f2bf_u(a0.w) << 16);
            af.u[2] = f2bf_u(a1.x) | (f2bf_u(a1.y) << 16);
            af.u[3] = f2bf_u(a1.z) | (f2bf_u(a1.w) << 16);
            afrg[kb] = af.s;
        }

        // 8 MFMAs (4 col-tiles x K=64)
        f32x4 acc[4];
        #pragma unroll
        for (int ct = 0; ct < 4; ++ct) {
            f32x4 c0 = {0.f, 0.f, 0.f, 0.f};
            c0 = __builtin_amdgcn_mfma_f32_16x16x32_bf16(afrg[0], bfrg[ct][0], c0, 0, 0, 0);
            c0 = __builtin_amdgcn_mfma_f32_16x16x32_bf16(afrg[1], bfrg[ct][1], c0, 0, 0, 0);
            acc[ct] = c0;
        }

        // epilogue into wave-private image
        // C/D layout: col = lane&15, row = (lane>>4)*4 + reg (HW-verified)
        #pragma unroll
        for (int ct = 0; ct < 4; ++ct)
            #pragma unroll
            for (int rg = 0; rg < 4; ++rg)
                img[(kslot * 4 + rg) * DIMV + 1 + ct * 16 + lrow] = acc[ct][rg];
        if (l < 16) img[l * DIMV] = x0v[i];

        // wave-local LDS drain (no block barrier), then contiguous stores
        asm volatile("s_waitcnt lgkmcnt(0)" ::: "memory");
        __builtin_amdgcn_sched_barrier(0);

        {
            float4* og = (float4*)(out + (row0 + i * 16) * DIMV);  // 16B aligned
            const float4* iv = (const float4*)img;
            #pragma unroll
            for (int p = 0; p < 4; ++p) og[p * 64 + l] = iv[p * 64 + l];
            if (l < 4) og[256 + l] = iv[256 + l];
        }
        // next iteration's epilogue writes are same-wave DS ops issued in
        // program order after these reads -> WAR-safe without extra waits.
    }
}

extern "C" void kernel_launch(void* const* d_in, const int* in_sizes, int n_in,
                              void* d_out, int out_size, void* d_ws, size_t ws_size,
                              hipStream_t stream) {
    const float* x         = (const float*)d_in[0];
    const int*   r_idx     = (const int*)d_in[1];
    const float* emb       = (const float*)d_in[2];
    const float* flip_sign = (const float*)d_in[3];
    float* out = (float*)d_out;
    unsigned short* WgT = (unsigned short*)d_ws;   // 512*64*64*2 = 4 MB bf16 W^T

    build_W<<<NUM_EMB, 256, 0, stream>>>(emb, flip_sign, r_idx, WgT, out);
    apply_W<<<BB, 256, 0, stream>>>(x, r_idx, WgT, out);
}

// Round 14
// 78.166 us; speedup vs baseline: 1.0366x; 1.0176x over previous
//
#include <hip/hip_runtime.h>
#include <math.h>

#define NUM_EMB 512
#define DIMV 65          // 65
#define DD   64          // DIM-1
#define BB   2048
#define NN   256
#define TILEF 1040       // 16 rows x 65 floats per tile
#define WTILES 8         // tiles per wave (wave owns 128 rows = half a b)
#define GRID_APPLY ((BB * NN) / (128 * 4))   // 1024 blocks (4 waves each)

typedef short short8 __attribute__((ext_vector_type(8)));   // 8 bf16 (4 VGPR)
typedef float f32x4  __attribute__((ext_vector_type(4)));   // MFMA acc

__device__ __forceinline__ float gelu_exact(float x) {
    return 0.5f * x * (1.0f + erff(x * 0.7071067811865475f));
}

// fp32 -> bf16, round-to-nearest-even, deterministic
__device__ __forceinline__ unsigned f2bf_u(float f) {
    unsigned u = __builtin_bit_cast(unsigned, f);
    u += 0x7FFFu + ((u >> 16) & 1u);
    return u >> 16;
}
__device__ __forceinline__ unsigned short f2bf(float f) {
    return (unsigned short)f2bf_u(f);
}

// ---------------------------------------------------------------------------
// Kernel 1: build W[e] = H0 @ ... @ H63 (Householder matvec + rank-1 update),
// scale last column, store TRANSPOSED bf16: WgT[e][c][d] = bf16(W[e][d][c]).
// Echoes r_idx into the out tail.
// ---------------------------------------------------------------------------
__global__ __launch_bounds__(256) void build_W(const float* __restrict__ emb,
                                               const float* __restrict__ flip_sign,
                                               const int*   __restrict__ r_idx,
                                               unsigned short* __restrict__ WgT,
                                               float* __restrict__ out) {
    __shared__ float v_lds[DD * DD];
    __shared__ float s_lds[DD];
    const int e = blockIdx.x;
    const int t = threadIdx.x;
    const int r = t >> 2;
    const int q = t & 3;

    const float* erow = emb + (size_t)e * (DD * DD);
    #pragma unroll
    for (int p = 0; p < 16; ++p) {
        int idx = p * 256 + t;
        v_lds[idx] = gelu_exact(erow[idx]);
    }

    // r_idx passthrough: output 1 lives at out[BB*NN*DIMV + b]
    if (t < 4) {
        int bi = e * 4 + t;
        out[(size_t)BB * NN * DIMV + bi] = (float)r_idx[bi];
    }
    __syncthreads();

    {
        const float* vr = &v_lds[r * DD + q * 16];
        float ss = 0.f;
        #pragma unroll
        for (int k = 0; k < 16; ++k) ss += vr[k] * vr[k];
        ss += __shfl_xor(ss, 1);
        ss += __shfl_xor(ss, 2);
        if (q == 0) s_lds[r] = 2.0f / ss;
    }
    __syncthreads();

    float Wq[16];
    #pragma unroll
    for (int k = 0; k < 16; ++k) Wq[k] = ((q * 16 + k) == r) ? 1.0f : 0.0f;

    float vv[16], nv[16];
    {
        const float* vr = &v_lds[q * 16];
        *(float4*)&nv[0]  = *(const float4*)&vr[0];
        *(float4*)&nv[4]  = *(const float4*)&vr[4];
        *(float4*)&nv[8]  = *(const float4*)&vr[8];
        *(float4*)&nv[12] = *(const float4*)&vr[12];
    }

    for (int w = 0; w < DD; ++w) {
        #pragma unroll
        for (int k = 0; k < 16; ++k) vv[k] = nv[k];
        if (w < DD - 1) {
            const float* vr = &v_lds[(w + 1) * DD + q * 16];
            *(float4*)&nv[0]  = *(const float4*)&vr[0];
            *(float4*)&nv[4]  = *(const float4*)&vr[4];
            *(float4*)&nv[8]  = *(const float4*)&vr[8];
            *(float4*)&nv[12] = *(const float4*)&vr[12];
        }
        float p0 = Wq[0] * vv[0],  p1 = Wq[1] * vv[1];
        float p2 = Wq[2] * vv[2],  p3 = Wq[3] * vv[3];
        #pragma unroll
        for (int k = 4; k < 16; k += 4) {
            p0 += Wq[k]     * vv[k];
            p1 += Wq[k + 1] * vv[k + 1];
            p2 += Wq[k + 2] * vv[k + 2];
            p3 += Wq[k + 3] * vv[k + 3];
        }
        float p = (p0 + p1) + (p2 + p3);
        p += __shfl_xor(p, 1);
        p += __shfl_xor(p, 2);
        const float sc = s_lds[w] * p;
        #pragma unroll
        for (int k = 0; k < 16; ++k) Wq[k] -= sc * vv[k];
    }

    if (q == 3) Wq[15] *= flip_sign[0];

    // store transposed bf16: WgT[e][c][d] with c = 16q+k, d = r
    unsigned short* wd = WgT + (size_t)e * (DD * DD) + r;
    #pragma unroll
    for (int k = 0; k < 16; ++k)
        wd[(16 * q + k) * DD] = f2bf(Wq[k]);
}

// ---------------------------------------------------------------------------
// Kernel 2 (MFMA + global_load_lds DMA pipeline, wave-autonomous, 0 barriers):
//   out[.,0]=x[.,0]; out[.,1+c]=sum_d x[.,1+d]*W[d][c]
// Grid 1024 x 256thr = 4096 waves; wave gw owns 128 consecutive rows
// (half of b = gw>>1 -> ONE B-matrix), as 8 x 16-row tiles, with a private
// double-buffered LDS image (2 x 1040 floats). No __syncthreads at all.
// Staging uses __builtin_amdgcn_global_load_lds (async DMA, NO VGPRs ->
// the register allocator CANNOT serialize it; fixes the R6-R13 invariant).
// Per tile i:
//   - issue 5 DMA loads of tile i+1 into buf^1 (4 x 16B-wide + masked tail)
//   - s_waitcnt vmcnt(5|10)  [counted, never 0: tile i+1 loads + prev
//     stores stay in flight -- T4]
//   - frag reads (b32, <=2-way bank = free), f2bf pack, 8 MFMA
//   - epilogue acc -> image cols 1..64 (col-0 survives from DMA)
//   - contiguous float4 stores of the image
// vmcnt bookkeeping (in-order retire): queue at iter-i wait =
//   [L(i) | S(i-1):5 | L(i+1):5] -> vmcnt(10) ensures L(i) done
//   (i=0: only L(1) newer -> vmcnt(5); i=7: no L(8) -> vmcnt(5)).
// ---------------------------------------------------------------------------
__global__ __launch_bounds__(256) void apply_W(const float* __restrict__ x,
                                               const int*   __restrict__ r_idx,
                                               const unsigned short* __restrict__ WgT,
                                               float* __restrict__ out) {
    __shared__ alignas(16) float IMG[4][2 * TILEF];   // 4 waves x 8320 B
    const int t = threadIdx.x;
    const int w = t >> 6;
    const int l = t & 63;
    const int lrow  = l & 15;
    const int kslot = l >> 4;

    const int    gw   = blockIdx.x * 4 + w;       // global wave id (< 4096)
    const size_t row0 = (size_t)gw * 128;         // wave's 128 rows
    const int    b    = gw >> 1;                  // half-b per wave

    const int e = r_idx[b];                       // uniform scalar
    float* img = IMG[w];
    const float* xw = x   + row0 * DIMV;          // 8320 floats (8 tiles)
    float*       ow = out + row0 * DIMV;

    // ---- B fragments (VGPR loads, 8KB table, L2/L3-hot) ----
    const unsigned short* wb = WgT + (size_t)e * (DD * DD);
    short8 bfrg[4][2];
    #pragma unroll
    for (int ct = 0; ct < 4; ++ct)
        #pragma unroll
        for (int kb = 0; kb < 2; ++kb)
            bfrg[ct][kb] = *(const short8*)(wb + (ct * 16 + lrow) * DD + kb * 32 + kslot * 8);

    // ---- DMA issue: 5 async loads of one tile into buf (i&1) ----
    auto issue_loads = [&](int i) {
        const float* g = xw + (size_t)i * TILEF;
        float* d = img + (i & 1) * TILEF;
        __builtin_amdgcn_global_load_lds((const unsigned*)(g + 0   + 4 * l), (unsigned*)(d + 0),    16, 0, 0);
        __builtin_amdgcn_global_load_lds((const unsigned*)(g + 256 + 4 * l), (unsigned*)(d + 256),  16, 0, 0);
        __builtin_amdgcn_global_load_lds((const unsigned*)(g + 512 + 4 * l), (unsigned*)(d + 512),  16, 0, 0);
        __builtin_amdgcn_global_load_lds((const unsigned*)(g + 768 + 4 * l), (unsigned*)(d + 768),  16, 0, 0);
        if (l < 4)   // 64B tail (floats 1024..1039); masked lanes still 1 vmcnt op
            __builtin_amdgcn_global_load_lds((const unsigned*)(g + 1024 + 4 * l), (unsigned*)(d + 1024), 16, 0, 0);
    };

    // ---- compute + store one tile (buffer i&1 is DMA-complete) ----
    auto do_tile = [&](int i) {
        const float* buf = img + (i & 1) * TILEF;
        // A fragments: 8 b32 LDS reads per kb (row base 65*lrow+1 is only
        // 4B-aligned -> scalar reads; banks (lrow+c) -> <=2-way = free)
        short8 afrg[2];
        #pragma unroll
        for (int kb = 0; kb < 2; ++kb) {
            const float* xp = buf + lrow * DIMV + 1 + kb * 32 + kslot * 8;
            union { short8 s; unsigned u[4]; } af;
            #pragma unroll
            for (int jj = 0; jj < 4; ++jj)
                af.u[jj] = f2bf_u(xp[2 * jj]) | (f2bf_u(xp[2 * jj + 1]) << 16);
            afrg[kb] = af.s;
        }

        // 8 MFMAs (4 col-tiles x K=64)
        f32x4 acc[4];
        #pragma unroll
        for (int ct = 0; ct < 4; ++ct) {
            f32x4 c0 = {0.f, 0.f, 0.f, 0.f};
            c0 = __builtin_amdgcn_mfma_f32_16x16x32_bf16(afrg[0], bfrg[ct][0], c0, 0, 0, 0);
            c0 = __builtin_amdgcn_mfma_f32_16x16x32_bf16(afrg[1], bfrg[ct][1], c0, 0, 0, 0);
            acc[ct] = c0;
        }

        // epilogue into image cols 1..64 (C/D: col=lane&15, row=(l>>4)*4+reg)
        float* bufw = img + (i & 1) * TILEF;
        #pragma unroll
        for (int ct = 0; ct < 4; ++ct)
            #pragma unroll
            for (int rg = 0; rg < 4; ++rg)
                bufw[(kslot * 4 + rg) * DIMV + 1 + ct * 16 + lrow] = acc[ct][rg];
        // (col-0 dwords in the image keep their DMA-loaded x values)

        // contiguous float4 stores (same-wave DS FIFO orders write->read;
        // compiler inserts lgkmcnt for the data returns)
        float4* og = (float4*)(ow + (size_t)i * TILEF);
        const float4* iv = (const float4*)bufw;
        #pragma unroll
        for (int p = 0; p < 4; ++p) og[p * 64 + l] = iv[p * 64 + l];
        if (l < 4) og[256 + l] = iv[256 + l];
    };

    // ---- prologue: tiles 0 and 1 in flight ----
    issue_loads(0);
    issue_loads(1);
    __builtin_amdgcn_sched_barrier(0);

#define TILE_STEP(I, VMSTR)                                   \
    do {                                                      \
        if ((I) + 1 < WTILES) issue_loads((I) + 1);           \
        __builtin_amdgcn_sched_barrier(0);                    \
        asm volatile("s_waitcnt " VMSTR ::: "memory");        \
        __builtin_amdgcn_sched_barrier(0);                    \
        do_tile(I);                                           \
    } while (0)

    TILE_STEP(0, "vmcnt(5)");    // newer: L(1)=5
    TILE_STEP(1, "vmcnt(10)");   // newer: S(0)=5 + L(2)=5
    TILE_STEP(2, "vmcnt(10)");
    TILE_STEP(3, "vmcnt(10)");
    TILE_STEP(4, "vmcnt(10)");
    TILE_STEP(5, "vmcnt(10)");
    TILE_STEP(6, "vmcnt(10)");
    TILE_STEP(7, "vmcnt(5)");    // newer: S(6)=5 only
#undef TILE_STEP
}

extern "C" void kernel_launch(void* const* d_in, const int* in_sizes, int n_in,
                              void* d_out, int out_size, void* d_ws, size_t ws_size,
                              hipStream_t stream) {
    const float* x         = (const float*)d_in[0];
    const int*   r_idx     = (const int*)d_in[1];
    const float* emb       = (const float*)d_in[2];
    const float* flip_sign = (const float*)d_in[3];
    float* out = (float*)d_out;
    unsigned short* WgT = (unsigned short*)d_ws;   // 512*64*64*2 = 4 MB bf16 W^T

    build_W<<<NUM_EMB, 256, 0, stream>>>(emb, flip_sign, r_idx, WgT, out);
    apply_W<<<GRID_APPLY, 256, 0, stream>>>(x, r_idx, WgT, out);
}

// Round 16
// 69.236 us; speedup vs baseline: 1.1703x; 1.1290x over previous
//
#include <hip/hip_runtime.h>
#include <math.h>

#define NUM_EMB 512
#define DIMV 65          // 65
#define DD   64          // DIM-1
#define BB   2048
#define NN   256
#define TILEF 1040       // 16 rows x 65 floats per tile
#define WTILES 8         // tiles per wave (wave owns 128 rows = half a b)
#define GRID_APPLY ((BB * NN) / (128 * 4))   // 1024 blocks (4 waves each)

typedef short short8 __attribute__((ext_vector_type(8)));   // 8 bf16 (4 VGPR)
typedef float f32x4  __attribute__((ext_vector_type(4)));   // MFMA acc
typedef float fv4    __attribute__((ext_vector_type(4)));   // ext-vector float4
                                                            // (nt-store compatible)

__device__ __forceinline__ float gelu_exact(float x) {
    return 0.5f * x * (1.0f + erff(x * 0.7071067811865475f));
}

// fp32 -> bf16, round-to-nearest-even, deterministic
__device__ __forceinline__ unsigned f2bf_u(float f) {
    unsigned u = __builtin_bit_cast(unsigned, f);
    u += 0x7FFFu + ((u >> 16) & 1u);
    return u >> 16;
}
__device__ __forceinline__ unsigned short f2bf(float f) {
    return (unsigned short)f2bf_u(f);
}

// ---------------------------------------------------------------------------
// Kernel 1: build W[e] = H0 @ ... @ H63 (Householder matvec + rank-1 update),
// scale last column, store TRANSPOSED bf16: WgT[e][c][d] = bf16(W[e][d][c]).
// Echoes r_idx into the out tail.
// ---------------------------------------------------------------------------
__global__ __launch_bounds__(256) void build_W(const float* __restrict__ emb,
                                               const float* __restrict__ flip_sign,
                                               const int*   __restrict__ r_idx,
                                               unsigned short* __restrict__ WgT,
                                               float* __restrict__ out) {
    __shared__ float v_lds[DD * DD];
    __shared__ float s_lds[DD];
    const int e = blockIdx.x;
    const int t = threadIdx.x;
    const int r = t >> 2;
    const int q = t & 3;

    const float* erow = emb + (size_t)e * (DD * DD);
    #pragma unroll
    for (int p = 0; p < 16; ++p) {
        int idx = p * 256 + t;
        v_lds[idx] = gelu_exact(erow[idx]);
    }

    // r_idx passthrough: output 1 lives at out[BB*NN*DIMV + b]
    if (t < 4) {
        int bi = e * 4 + t;
        out[(size_t)BB * NN * DIMV + bi] = (float)r_idx[bi];
    }
    __syncthreads();

    {
        const float* vr = &v_lds[r * DD + q * 16];
        float ss = 0.f;
        #pragma unroll
        for (int k = 0; k < 16; ++k) ss += vr[k] * vr[k];
        ss += __shfl_xor(ss, 1);
        ss += __shfl_xor(ss, 2);
        if (q == 0) s_lds[r] = 2.0f / ss;
    }
    __syncthreads();

    float Wq[16];
    #pragma unroll
    for (int k = 0; k < 16; ++k) Wq[k] = ((q * 16 + k) == r) ? 1.0f : 0.0f;

    float vv[16], nv[16];
    {
        const float* vr = &v_lds[q * 16];
        *(float4*)&nv[0]  = *(const float4*)&vr[0];
        *(float4*)&nv[4]  = *(const float4*)&vr[4];
        *(float4*)&nv[8]  = *(const float4*)&vr[8];
        *(float4*)&nv[12] = *(const float4*)&vr[12];
    }

    for (int w = 0; w < DD; ++w) {
        #pragma unroll
        for (int k = 0; k < 16; ++k) vv[k] = nv[k];
        if (w < DD - 1) {
            const float* vr = &v_lds[(w + 1) * DD + q * 16];
            *(float4*)&nv[0]  = *(const float4*)&vr[0];
            *(float4*)&nv[4]  = *(const float4*)&vr[4];
            *(float4*)&nv[8]  = *(const float4*)&vr[8];
            *(float4*)&nv[12] = *(const float4*)&vr[12];
        }
        float p0 = Wq[0] * vv[0],  p1 = Wq[1] * vv[1];
        float p2 = Wq[2] * vv[2],  p3 = Wq[3] * vv[3];
        #pragma unroll
        for (int k = 4; k < 16; k += 4) {
            p0 += Wq[k]     * vv[k];
            p1 += Wq[k + 1] * vv[k + 1];
            p2 += Wq[k + 2] * vv[k + 2];
            p3 += Wq[k + 3] * vv[k + 3];
        }
        float p = (p0 + p1) + (p2 + p3);
        p += __shfl_xor(p, 1);
        p += __shfl_xor(p, 2);
        const float sc = s_lds[w] * p;
        #pragma unroll
        for (int k = 0; k < 16; ++k) Wq[k] -= sc * vv[k];
    }

    if (q == 3) Wq[15] *= flip_sign[0];

    // store transposed bf16: WgT[e][c][d] with c = 16q+k, d = r
    unsigned short* wd = WgT + (size_t)e * (DD * DD) + r;
    #pragma unroll
    for (int k = 0; k < 16; ++k)
        wd[(16 * q + k) * DD] = f2bf(Wq[k]);
}

// ---------------------------------------------------------------------------
// Kernel 2 (MFMA + global_load_lds DMA pipeline + NON-TEMPORAL stores):
//   out[.,0]=x[.,0]; out[.,1+c]=sum_d x[.,1+d]*W[d][c]
// Identical to R14 except the output stores are __builtin_nontemporal_store
// via ext-vector fv4 (global_store_dwordx4 ... nt): out is write-once;
// bypassing L2/L3 write-allocate removes cache churn against the x reads
// (the single untested variable after sweeping staging mechanism / sync
// structure / pipeline depth, all of which converge at ~78us).
// Structure: grid 1024x256, wave owns 128 rows as 8 x 16-row tiles, private
// double-buffered LDS image, zero block barriers, counted vmcnt (never 0):
//   queue at iter-i wait = [L(i):5 | S(i-1):5 | L(i+1):5] -> vmcnt(10)
//   (i=0: vmcnt(5); i=7: vmcnt(5)).
// ---------------------------------------------------------------------------
__global__ __launch_bounds__(256) void apply_W(const float* __restrict__ x,
                                               const int*   __restrict__ r_idx,
                                               const unsigned short* __restrict__ WgT,
                                               float* __restrict__ out) {
    __shared__ alignas(16) float IMG[4][2 * TILEF];   // 4 waves x 8320 B
    const int t = threadIdx.x;
    const int w = t >> 6;
    const int l = t & 63;
    const int lrow  = l & 15;
    const int kslot = l >> 4;

    const int    gw   = blockIdx.x * 4 + w;       // global wave id (< 4096)
    const size_t row0 = (size_t)gw * 128;         // wave's 128 rows
    const int    b    = gw >> 1;                  // half-b per wave

    const int e = r_idx[b];                       // uniform scalar
    float* img = IMG[w];
    const float* xw = x   + row0 * DIMV;          // 8320 floats (8 tiles)
    float*       ow = out + row0 * DIMV;

    // ---- B fragments (VGPR loads, 8KB table, L2/L3-hot) ----
    const unsigned short* wb = WgT + (size_t)e * (DD * DD);
    short8 bfrg[4][2];
    #pragma unroll
    for (int ct = 0; ct < 4; ++ct)
        #pragma unroll
        for (int kb = 0; kb < 2; ++kb)
            bfrg[ct][kb] = *(const short8*)(wb + (ct * 16 + lrow) * DD + kb * 32 + kslot * 8);

    // ---- DMA issue: 5 async loads of one tile into buf (i&1) ----
    auto issue_loads = [&](int i) {
        const float* g = xw + (size_t)i * TILEF;
        float* d = img + (i & 1) * TILEF;
        __builtin_amdgcn_global_load_lds((const unsigned*)(g + 0   + 4 * l), (unsigned*)(d + 0),    16, 0, 0);
        __builtin_amdgcn_global_load_lds((const unsigned*)(g + 256 + 4 * l), (unsigned*)(d + 256),  16, 0, 0);
        __builtin_amdgcn_global_load_lds((const unsigned*)(g + 512 + 4 * l), (unsigned*)(d + 512),  16, 0, 0);
        __builtin_amdgcn_global_load_lds((const unsigned*)(g + 768 + 4 * l), (unsigned*)(d + 768),  16, 0, 0);
        if (l < 4)   // 64B tail (floats 1024..1039)
            __builtin_amdgcn_global_load_lds((const unsigned*)(g + 1024 + 4 * l), (unsigned*)(d + 1024), 16, 0, 0);
    };

    // ---- compute + store one tile (buffer i&1 is DMA-complete) ----
    auto do_tile = [&](int i) {
        const float* buf = img + (i & 1) * TILEF;
        // A fragments: 8 b32 LDS reads per kb (<=2-way bank = free)
        short8 afrg[2];
        #pragma unroll
        for (int kb = 0; kb < 2; ++kb) {
            const float* xp = buf + lrow * DIMV + 1 + kb * 32 + kslot * 8;
            union { short8 s; unsigned u[4]; } af;
            #pragma unroll
            for (int jj = 0; jj < 4; ++jj)
                af.u[jj] = f2bf_u(xp[2 * jj]) | (f2bf_u(xp[2 * jj + 1]) << 16);
            afrg[kb] = af.s;
        }

        // 8 MFMAs (4 col-tiles x K=64)
        f32x4 acc[4];
        #pragma unroll
        for (int ct = 0; ct < 4; ++ct) {
            f32x4 c0 = {0.f, 0.f, 0.f, 0.f};
            c0 = __builtin_amdgcn_mfma_f32_16x16x32_bf16(afrg[0], bfrg[ct][0], c0, 0, 0, 0);
            c0 = __builtin_amdgcn_mfma_f32_16x16x32_bf16(afrg[1], bfrg[ct][1], c0, 0, 0, 0);
            acc[ct] = c0;
        }

        // epilogue into image cols 1..64 (C/D: col=lane&15, row=(l>>4)*4+reg)
        float* bufw = img + (i & 1) * TILEF;
        #pragma unroll
        for (int ct = 0; ct < 4; ++ct)
            #pragma unroll
            for (int rg = 0; rg < 4; ++rg)
                bufw[(kslot * 4 + rg) * DIMV + 1 + ct * 16 + lrow] = acc[ct][rg];
        // (col-0 dwords in the image keep their DMA-loaded x values)

        // contiguous NON-TEMPORAL stores via ext-vector fv4
        fv4* og = (fv4*)(ow + (size_t)i * TILEF);
        const fv4* iv = (const fv4*)bufw;
        #pragma unroll
        for (int p = 0; p < 4; ++p) {
            fv4 val = iv[p * 64 + l];
            __builtin_nontemporal_store(val, &og[p * 64 + l]);
        }
        if (l < 4) {
            fv4 val = iv[256 + l];
            __builtin_nontemporal_store(val, &og[256 + l]);
        }
    };

    // ---- prologue: tiles 0 and 1 in flight ----
    issue_loads(0);
    issue_loads(1);
    __builtin_amdgcn_sched_barrier(0);

#define TILE_STEP(I, VMSTR)                                   \
    do {                                                      \
        if ((I) + 1 < WTILES) issue_loads((I) + 1);           \
        __builtin_amdgcn_sched_barrier(0);                    \
        asm volatile("s_waitcnt " VMSTR ::: "memory");        \
        __builtin_amdgcn_sched_barrier(0);                    \
        do_tile(I);                                           \
    } while (0)

    TILE_STEP(0, "vmcnt(5)");    // newer: L(1)=5
    TILE_STEP(1, "vmcnt(10)");   // newer: S(0)=5 + L(2)=5
    TILE_STEP(2, "vmcnt(10)");
    TILE_STEP(3, "vmcnt(10)");
    TILE_STEP(4, "vmcnt(10)");
    TILE_STEP(5, "vmcnt(10)");
    TILE_STEP(6, "vmcnt(10)");
    TILE_STEP(7, "vmcnt(5)");    // newer: S(6)=5 only
#undef TILE_STEP
}

extern "C" void kernel_launch(void* const* d_in, const int* in_sizes, int n_in,
                              void* d_out, int out_size, void* d_ws, size_t ws_size,
                              hipStream_t stream) {
    const float* x         = (const float*)d_in[0];
    const int*   r_idx     = (const int*)d_in[1];
    const float* emb       = (const float*)d_in[2];
    const float* flip_sign = (const float*)d_in[3];
    float* out = (float*)d_out;
    unsigned short* WgT = (unsigned short*)d_ws;   // 512*64*64*2 = 4 MB bf16 W^T

    build_W<<<NUM_EMB, 256, 0, stream>>>(emb, flip_sign, r_idx, WgT, out);
    apply_W<<<GRID_APPLY, 256, 0, stream>>>(x, r_idx, WgT, out);
}